// Round 3
// baseline (2232.752 us; speedup 1.0000x reference)
//
#include <hip/hip_runtime.h>

#define EPS 0.01f
#define TSTEPS 2048
#define BATCH 64
// 2*log2(e): exp(2x) = exp2(x * TWOLOG2E). W and xu are pre-scaled by this
// at pack time so the tanh argument arrives ready for v_exp_f32 (exp2).
#define TWOLOG2E 2.8853900817779268f

typedef _Float16 half8 __attribute__((ext_vector_type(8)));
typedef _Float16 half4 __attribute__((ext_vector_type(4)));
typedef float f32x4 __attribute__((ext_vector_type(4)));

// Workgroup barrier WITHOUT the vmcnt(0) drain the compiler emits for
// __syncthreads(). LDS visibility needs lgkmcnt(0) only; global loads
// (xu prefetch) and stores (h writeback) are lane-private and stay in
// flight across the barrier (AITER-style fine-grained pipelining).
#define LDS_BARRIER() asm volatile("s_waitcnt lgkmcnt(0)\n\ts_barrier" ::: "memory")

// ---------------------------------------------------------------------------
// prep_mc_pack: build Mc^T directly as f16 MFMA A-operand fragments.
// 16-wave decomposition: wave w (0..15) owns 16 output cols 16w..16w+15.
// frag id f = (w*2 + mt)*8 + kk;  mt 0 = A-part (from B), mt 1 = W-part
// (from C, PRE-SCALED by TWOLOG2E so the scan's exp2 needs no extra mul).
// A-frag layout: lane l holds A[m=l&15][k=kk*32+(l>>4)*8+j], j=0..7, where
// A-operand element (c,k) = Mat[k][c], Mat = Src - 0.6*Src^T - 0.01I.
// ---------------------------------------------------------------------------
__global__ void prep_mc_pack(const float* __restrict__ Bm, const float* __restrict__ Cm,
                             _Float16* __restrict__ mcPack) {
    int f = blockIdx.x;       // 0..255
    int lane = threadIdx.x;   // 0..63
    int w = f >> 4;           // wave 0..15
    int mt = (f >> 3) & 1;    // 0=A, 1=W
    int kk = f & 7;
    const float* Src = (mt == 0) ? Bm : Cm;
    float scale = (mt == 0) ? 1.0f : TWOLOG2E;
    int c = 16 * w + (lane & 15);
    int k0 = kk * 32 + (lane >> 4) * 8;
    long off = ((long)f * 64 + lane) * 8;
#pragma unroll
    for (int j = 0; j < 8; ++j) {
        int k = k0 + j;
        float diag = (k == c) ? 0.01f : 0.0f;
        float v = scale * (Src[(long)k * 256 + c] - 0.6f * Src[(long)c * 256 + k] - diag);
        mcPack[off + j] = (_Float16)v;
    }
}

// ---------------------------------------------------------------------------
// pack_u: U (256x256 fp32) -> f16 B-operand fragments for xu_gemm.
// ---------------------------------------------------------------------------
__global__ void pack_u(const float* __restrict__ U, _Float16* __restrict__ up) {
    int t = blockIdx.x * 64 + threadIdx.x;
    int lane = t & 63;
    int tile = t >> 6;      // kk*16 + nn
    int nn = tile & 15;
    int kk = tile >> 4;
    int krow = kk * 32 + (lane >> 4) * 8;
    int col = nn * 16 + (lane & 15);
    long off = (long)t * 8;
#pragma unroll
    for (int jj = 0; jj < 8; ++jj) {
        up[off + jj] = (_Float16)U[(krow + jj) * 256 + col];
    }
}

// ---------------------------------------------------------------------------
// xu_gemm: out[r][n] = (sum_k x[r][k]*U[k][n] + bias[n]) * TWOLOG2E
// (pre-scaled tanh argument contribution). Writes into d_out; scan
// overwrites in place with h.
// ---------------------------------------------------------------------------
__global__ __launch_bounds__(256) void xu_gemm(const float* __restrict__ x,
                                               const _Float16* __restrict__ up,
                                               const float* __restrict__ bias,
                                               float* __restrict__ out) {
    int wave = threadIdx.x >> 6;
    int lane = threadIdx.x & 63;
    int m = lane & 15;
    int quad = lane >> 4;
    long row0 = (long)blockIdx.x * 64 + wave * 16;
    const float* xrow = x + (row0 + m) * 256 + quad * 8;

    f32x4 acc[16];
#pragma unroll
    for (int nn = 0; nn < 16; ++nn) acc[nn] = (f32x4){0.f, 0.f, 0.f, 0.f};

#pragma unroll
    for (int kk = 0; kk < 8; ++kk) {
        f32x4 xa = *(const f32x4*)(xrow + kk * 32);
        f32x4 xb = *(const f32x4*)(xrow + kk * 32 + 4);
        half8 af;
        af[0] = (_Float16)xa[0]; af[1] = (_Float16)xa[1];
        af[2] = (_Float16)xa[2]; af[3] = (_Float16)xa[3];
        af[4] = (_Float16)xb[0]; af[5] = (_Float16)xb[1];
        af[6] = (_Float16)xb[2]; af[7] = (_Float16)xb[3];
        const _Float16* ub = up + ((long)kk * 1024 + lane) * 8;
#pragma unroll
        for (int nn = 0; nn < 16; ++nn) {
            half8 bf = *(const half8*)(ub + (long)nn * 512);
            acc[nn] = __builtin_amdgcn_mfma_f32_16x16x32_f16(af, bf, acc[nn], 0, 0, 0);
        }
    }
#pragma unroll
    for (int nn = 0; nn < 16; ++nn) {
        int col = nn * 16 + m;
        float bv = bias[col];
#pragma unroll
        for (int i = 0; i < 4; ++i) {
            out[(row0 + quad * 4 + i) * 256 + col] = (acc[nn][i] + bv) * TWOLOG2E;
        }
    }
}

// ---------------------------------------------------------------------------
// scan_kernel: grid=4 (16 batch rows each), 1024 threads = 16 waves,
// 4 waves/SIMD (deep TLP to hide the per-step serial chain:
// barrier -> ds_read h -> MFMA chains -> EW -> LDS write -> barrier).
// Wave w owns 16 output cols (1 A-tile + 1 W-tile = 16 MFMAs/step);
// Mc fragments stationary (64 regs -> AGPRs); h double-buffered in LDS as
// f16 B-frags; xu read in-place from d_out (2-step prefetch, pre-scaled by
// TWOLOG2E) and overwritten with h_t.
//
// Elementwise folding: A-chain C-initialized with hs = h/EPS (own cols, in
// regs), W-chain with pre-scaled xu. Per element:
//   e = exp2(accW); r = rcp(e+1); hs' = accA + 1 - 2r; h = EPS*hs'.
// Register budget (4 waves/SIMD => <=128/wave): mcf 64 (AGPR) + hb 16
// (two-phase 4+4) + acc 8 + hs 4 + xq 8 + temps ~18 ~= 118.
// ---------------------------------------------------------------------------
__global__ __launch_bounds__(1024, 4) void scan_kernel(const _Float16* __restrict__ mcPack,
                                                       float* __restrict__ io) {
    const int tid = threadIdx.x;
    const int w = tid >> 6;       // 0..15
    const int lane = tid & 63;
    const int m = lane & 15;
    const int q = lane >> 4;
    const int b0 = blockIdx.x * 16;

    // Stationary A-operand fragments: 2 M-tiles (A,W) x 8 K-steps = 64 regs.
    half8 mcf[2][8];
#pragma unroll
    for (int mt = 0; mt < 2; ++mt)
#pragma unroll
        for (int kk = 0; kk < 8; ++kk)
            mcf[mt][kk] = *(const half8*)(mcPack + (((long)(w * 2 + mt) * 8 + kk) * 64 + lane) * 8);

    __shared__ _Float16 hB[2][4096];  // 2 x 8KB double buffer, h^T as B-frags

    // zero buffer 0 (h0 = 0): 1024 threads x 4 halfs
    {
        half4 z = (half4)(_Float16)0.0f;
        *(half4*)(&hB[0][tid * 4]) = z;
    }

    const int rdIdx = lane * 8;
    // wave w's 16 units live in frag kk'=w>>1, k_local base 16*(w&1):
    // element (batch m, unit 16w+4q+i) -> half index
    //   512*(w>>1) + 256*(w&1) + 128*(q>>1) + 8*m + 4*(q&1) + i
    const int wrIdx = 512 * (w >> 1) + 256 * (w & 1) + 128 * (q >> 1) + 8 * m + 4 * (q & 1);

    // per-lane global pointer: row b0+m, col 16w+4q.
    float* p = io + ((long)(b0 + m) * TSTEPS) * 256 + 16 * w + 4 * q;

    // hs = h/EPS for this lane's own output elements (acc layout), starts 0.
    f32x4 hs = (f32x4){0.f, 0.f, 0.f, 0.f};

    f32x4 xq[2];
    xq[0] = *(const f32x4*)(p);
    xq[1] = *(const f32x4*)(p + 256);
    __syncthreads();

    auto step = [&](int t, const _Float16* hbR, _Float16* hbW, f32x4& xc) {
        // ---- phase 1: read h frags 0..3, run chains kk=0..3 ----
        half8 hb0 = *(const half8*)(hbR + 0 * 512 + rdIdx);
        half8 hb1 = *(const half8*)(hbR + 1 * 512 + rdIdx);
        half8 hb2 = *(const half8*)(hbR + 2 * 512 + rdIdx);
        half8 hb3 = *(const half8*)(hbR + 3 * 512 + rdIdx);

        f32x4 aA = __builtin_amdgcn_mfma_f32_16x16x32_f16(mcf[0][0], hb0, hs, 0, 0, 0);
        f32x4 aW = __builtin_amdgcn_mfma_f32_16x16x32_f16(mcf[1][0], hb0, xc, 0, 0, 0);
        aA = __builtin_amdgcn_mfma_f32_16x16x32_f16(mcf[0][1], hb1, aA, 0, 0, 0);
        aW = __builtin_amdgcn_mfma_f32_16x16x32_f16(mcf[1][1], hb1, aW, 0, 0, 0);
        aA = __builtin_amdgcn_mfma_f32_16x16x32_f16(mcf[0][2], hb2, aA, 0, 0, 0);
        aW = __builtin_amdgcn_mfma_f32_16x16x32_f16(mcf[1][2], hb2, aW, 0, 0, 0);
        aA = __builtin_amdgcn_mfma_f32_16x16x32_f16(mcf[0][3], hb3, aA, 0, 0, 0);
        aW = __builtin_amdgcn_mfma_f32_16x16x32_f16(mcf[1][3], hb3, aW, 0, 0, 0);

        // ---- phase 2: read h frags 4..7, run chains kk=4..7 ----
        half8 hb4 = *(const half8*)(hbR + 4 * 512 + rdIdx);
        half8 hb5 = *(const half8*)(hbR + 5 * 512 + rdIdx);
        half8 hb6 = *(const half8*)(hbR + 6 * 512 + rdIdx);
        half8 hb7 = *(const half8*)(hbR + 7 * 512 + rdIdx);

        aA = __builtin_amdgcn_mfma_f32_16x16x32_f16(mcf[0][4], hb4, aA, 0, 0, 0);
        aW = __builtin_amdgcn_mfma_f32_16x16x32_f16(mcf[1][4], hb4, aW, 0, 0, 0);
        aA = __builtin_amdgcn_mfma_f32_16x16x32_f16(mcf[0][5], hb5, aA, 0, 0, 0);
        aW = __builtin_amdgcn_mfma_f32_16x16x32_f16(mcf[1][5], hb5, aW, 0, 0, 0);
        aA = __builtin_amdgcn_mfma_f32_16x16x32_f16(mcf[0][6], hb6, aA, 0, 0, 0);
        aW = __builtin_amdgcn_mfma_f32_16x16x32_f16(mcf[1][6], hb6, aW, 0, 0, 0);
        aA = __builtin_amdgcn_mfma_f32_16x16x32_f16(mcf[0][7], hb7, aA, 0, 0, 0);
        aW = __builtin_amdgcn_mfma_f32_16x16x32_f16(mcf[1][7], hb7, aW, 0, 0, 0);

        // ---- elementwise (4 elems): hs' = accA + 1 - 2*rcp(exp2(accW)+1) ----
        f32x4 hn;
#pragma unroll
        for (int i = 0; i < 4; ++i) {
            float e = __builtin_amdgcn_exp2f(aW[i]);
            float r = __builtin_amdgcn_rcpf(e + 1.0f);
            float hsv = fmaf(-2.0f, r, aA[i] + 1.0f);
            hs[i] = hsv;
            hn[i] = EPS * hsv;
        }
        half4 h4;
#pragma unroll
        for (int i = 0; i < 4; ++i) h4[i] = (_Float16)hn[i];
        *(half4*)(hbW + wrIdx) = h4;   // next-step B-frags (LDS)
        *(f32x4*)(p) = hn;             // h_t -> global out (in place)

        // ---- prefetch xu[t+2] (stays in flight across the barrier) ----
        if (t + 2 < TSTEPS) {
            xc = *(const f32x4*)(p + 512);
        }
        p += 256;
        LDS_BARRIER();  // lgkmcnt(0)-only barrier: no vmcnt drain
    };

    for (int t = 0; t < TSTEPS; t += 2) {
        step(t, hB[0], hB[1], xq[0]);
        step(t + 1, hB[1], hB[0], xq[1]);
    }
}

extern "C" void kernel_launch(void* const* d_in, const int* in_sizes, int n_in,
                              void* d_out, int out_size, void* d_ws, size_t ws_size,
                              hipStream_t stream) {
    const float* x    = (const float*)d_in[0];
    const float* C    = (const float*)d_in[1];
    const float* Bm   = (const float*)d_in[2];
    const float* U    = (const float*)d_in[3];
    const float* bias = (const float*)d_in[4];
    float* out = (float*)d_out;

    _Float16* mcPack = (_Float16*)d_ws;                         // 256 KB
    _Float16* up     = (_Float16*)((char*)d_ws + 262144);       // 128 KB

    prep_mc_pack<<<256, 64, 0, stream>>>(Bm, C, mcPack);
    pack_u<<<128, 64, 0, stream>>>(U, up);
    xu_gemm<<<2048, 256, 0, stream>>>(x, up, bias, out);
    scan_kernel<<<4, 1024, 0, stream>>>(mcPack, out);
}